// Round 7
// baseline (110432.471 us; speedup 1.0000x reference)
//
#include <hip/hip_runtime.h>
#include <stdint.h>

// Problem: D-FPS. points_xyz (16, 131072, 3) fp32 -> indices (16, 4096) int32.
//
// Round 7 design:
//  - Update: points in LDS (SoA float, conflict-free b32 reads) — r6-proven.
//  - Sync: private-line mailboxes. r6's collapse is explained by reader-flood:
//    512 wave0s tight-spinning agent-acquire loads on 4 shared lines/batch
//    starved the release-stores at the coherence point (r4 survived only
//    because its slow update throttled the spin duty cycle). Here every
//    spinning wave polls a line nobody else polls:
//      * block -> private slot line (coords + tagged dist/idx), leader reads
//      * leader -> private mailbox line per block (coords + tag), one reader
//    Winner coords travel in the messages; bxyz is never touched after
//    staging. Ring-2 parity + iteration tags as before (audited: tag-I
//    readers complete before any tag-I+2 overwrite).

#define BATCH   16
#define NSAMP   4096
#define NPTS    131072
#define NBLK    32                 // blocks per batch
#define TPB     512                // 8 waves
#define CHUNK   (NPTS / NBLK)      // 4096 points per block
#define PPT     (CHUNK / TPB)      // 8 points per thread
#define NWAVE   (TPB / 64)

typedef unsigned long long u64;
typedef unsigned int u32;

// 64 B line = 8 u64 words. Layout per line:
//   slot line:    w0 = (cx|cy)  w1 = (cz|idx)  w2 = dist<<32 | idx<<15 | tag
//   mailbox line: w0 = (cx|cy)  w1 = (cz|idx)  w2 = it<<32 | idx
// Poison 0xAA.. -> slot tag 0x2AAA (>4095), mb hi32 0xAAAAAAAA (!=it);
// zero-init -> 0; neither matches a live it in [1,4095].

static __device__ __forceinline__ u64 packf(float a, float b) {
    return ((u64)__float_as_uint(a) << 32) | (u64)__float_as_uint(b);
}

__global__ void fps_init_kernel(u64* __restrict__ ws) {
    int i = blockIdx.x * blockDim.x + threadIdx.x;
    if (i < BATCH * 2 * NBLK * 8 * 2) ws[i] = 0ull;   // slots + mailboxes
}

__global__ __launch_bounds__(TPB, 2) void fps_kernel(
        const float* __restrict__ xyz, int* __restrict__ out,
        u64* __restrict__ gws) {
    const int blk   = blockIdx.x;
    const int b     = blk & 15;        // batch: blk%8 = b%8 -> XCD affinity
    const int chunk = blk >> 4;        // leader = chunk 0
    const int tid   = threadIdx.x;
    const int w     = tid >> 6;
    const int lane  = tid & 63;

    const float* bxyz = xyz + (size_t)b * NPTS * 3;
    const int base = chunk * CHUNK;

    u64* slots = gws;                            // [BATCH][2][NBLK] lines
    u64* mbs   = gws + (size_t)BATCH * 2 * NBLK * 8;

    // ---- LDS: SoA points (conflict-free stride-1 b32 reads) + sync vars ----
    __shared__ float sx[CHUNK], sy[CHUNK], sz[CHUNK];   // 48 KB
    __shared__ u64 red[2][NWAVE];
    __shared__ u64 bcA[2], bcB[2];
    for (int i = tid; i < CHUNK; i += TPB) {
        size_t p = (size_t)(base + i) * 3;
        sx[i] = bxyz[p + 0];
        sy[i] = bxyz[p + 1];
        sz[i] = bxyz[p + 2];
    }
    if (tid < 2 * NWAVE) ((u64*)red)[tid] = ~0ull;   // invalid tag
    if (tid < 2) { bcA[tid] = ~0ull; bcB[tid] = ~0ull; }
    if (tid == 0 && chunk == 0) out[b * NSAMP] = 0;  // iter 0 emits index 0
    __syncthreads();   // staging visibility (only block-wide barrier)

    float pd[PPT];
#pragma unroll
    for (int k = 0; k < PPT; ++k) pd[k] = __builtin_inff();

    float cx = bxyz[0], cy = bxyz[1], cz = bxyz[2];

    for (int it = 1; it < NSAMP; ++it) {
        const int par = it & 1;
        u64* sl = slots + (((size_t)b * 2 + par) * NBLK) * 8;  // batch slot arr
        u64* ml = mbs   + (((size_t)b * 2 + par) * NBLK) * 8;  // batch mb arr

        // ---- update min-dists + local argmax (LDS + registers) ----
        // Verified arithmetic (round 2, absmax 0): FMA-contracted
        //   d = fma(dz,dz, fma(dy,dy, dx*dx)), subs exact-rounded.
        float bd = -1.0f;
        int   bk = 0;
#pragma unroll
        for (int k = 0; k < PPT; ++k) {
            int i = tid + TPB * k;
            float dx = __fsub_rn(sx[i], cx);
            float dy = __fsub_rn(sy[i], cy);
            float dz = __fsub_rn(sz[i], cz);
            float d  = __builtin_fmaf(dz, dz,
                         __builtin_fmaf(dy, dy, __fmul_rn(dx, dx)));
            float nd = fminf(pd[k], d);
            pd[k] = nd;
            // strict >: earliest k wins (gi ascends with k) = first-occurrence
            if (nd > bd) { bd = nd; bk = k; }
        }
        u32 gi = (u32)(base + tid + TPB * bk);
        u64 key = ((u64)__float_as_uint(bd) << 32) | (u64)(~gi);

        // ---- wave butterfly (max dist, then min index) ----
#pragma unroll
        for (int off = 1; off <= 32; off <<= 1) {
            u64 o = __shfl_xor(key, off, 64);
            key = key > o ? key : o;
        }
        if (lane == 0) {
            u32 db  = (u32)(key >> 32);
            u32 idx = ~(u32)key;
            __hip_atomic_store(&red[par][w],
                               ((u64)db << 32) | ((u64)idx << 15) | (u64)it,
                               __ATOMIC_RELEASE, __HIP_MEMORY_SCOPE_WORKGROUP);
        }

        if (w == 0) {
            // ---- combine the 8 wave entries from LDS ----
            u64 v; bool ok;
            do {
                v  = (lane < NWAVE)
                       ? __hip_atomic_load(&red[par][lane], __ATOMIC_ACQUIRE,
                                           __HIP_MEMORY_SCOPE_WORKGROUP)
                       : 0ull;
                ok = (lane < NWAVE) ? ((v & 0x7FFFull) == (u64)it) : true;
            } while (__ballot(ok) != ~0ull);
            u64 k2 = 0ull;
            if (lane < NWAVE) {
                u32 db  = (u32)(v >> 32);
                u32 idx = (u32)((v >> 15) & 0x1FFFFu);
                k2 = ((u64)db << 32) | (u64)(~idx);
            }
#pragma unroll
            for (int off = 1; off <= 4; off <<= 1) {
                u64 o = __shfl_xor(k2, off, 64);
                k2 = k2 > o ? k2 : o;
            }
            // ---- publish block winner WITH coords to this block's line ----
            if (lane == 0) {
                u32 widx = ~(u32)k2;
                u32 db   = (u32)(k2 >> 32);
                int li   = (int)widx - base;          // local LDS index
                u64* line = sl + (size_t)chunk * 8;
                __hip_atomic_store(&line[0], packf(sx[li], sy[li]),
                                   __ATOMIC_RELAXED, __HIP_MEMORY_SCOPE_AGENT);
                __hip_atomic_store(&line[1],
                                   ((u64)__float_as_uint(sz[li]) << 32) | widx,
                                   __ATOMIC_RELAXED, __HIP_MEMORY_SCOPE_AGENT);
                __hip_atomic_store(&line[2],
                                   ((u64)db << 32) | ((u64)widx << 15) | (u64)it,
                                   __ATOMIC_RELEASE, __HIP_MEMORY_SCOPE_AGENT);
            }

            if (chunk == 0) {
                // ---- LEADER: poll 32 private slot lines (lane i <-> line i) --
                u64 w2;
                do {
                    w2 = (lane < NBLK)
                           ? __hip_atomic_load(&sl[(size_t)lane * 8 + 2],
                                               __ATOMIC_ACQUIRE,
                                               __HIP_MEMORY_SCOPE_AGENT)
                           : 0ull;
                    ok = (lane < NBLK) ? ((w2 & 0x7FFFull) == (u64)it) : true;
                } while (__ballot(ok) != ~0ull);
                u64 w0 = 0, w1 = 0, kk = 0;
                if (lane < NBLK) {
                    w0 = __hip_atomic_load(&sl[(size_t)lane * 8 + 0],
                                           __ATOMIC_RELAXED,
                                           __HIP_MEMORY_SCOPE_AGENT);
                    w1 = __hip_atomic_load(&sl[(size_t)lane * 8 + 1],
                                           __ATOMIC_RELAXED,
                                           __HIP_MEMORY_SCOPE_AGENT);
                    u32 db  = (u32)(w2 >> 32);
                    u32 idx = (u32)((w2 >> 15) & 0x1FFFFu);
                    kk = ((u64)db << 32) | (u64)(~idx);
                }
                u64 km = kk;
#pragma unroll
                for (int off = 1; off <= 16; off <<= 1) {
                    u64 o = __shfl_xor(km, off, 64);
                    km = km > o ? km : o;
                }
                u64 mine = __ballot((lane < NBLK) && (kk == km));
                int wl = (int)__builtin_ctzll(mine);
                u64 ww0 = __shfl(w0, wl, 64);
                u64 ww1 = __shfl(w1, wl, 64);
                cx = __uint_as_float((u32)(ww0 >> 32));
                cy = __uint_as_float((u32)ww0);
                cz = __uint_as_float((u32)(ww1 >> 32));
                u32 widx = (u32)ww1;
                // ---- push result into 32 private mailboxes (lane-parallel) --
                if (lane < NBLK) {
                    u64* m = ml + (size_t)lane * 8;
                    __hip_atomic_store(&m[0], ww0, __ATOMIC_RELAXED,
                                       __HIP_MEMORY_SCOPE_AGENT);
                    __hip_atomic_store(&m[1], ww1, __ATOMIC_RELAXED,
                                       __HIP_MEMORY_SCOPE_AGENT);
                    __hip_atomic_store(&m[2], ((u64)(u32)it << 32) | widx,
                                       __ATOMIC_RELEASE,
                                       __HIP_MEMORY_SCOPE_AGENT);
                }
                if (lane == 0) out[b * NSAMP + it] = (int)widx;
            } else {
                // ---- FOLLOWER: spin only on OUR private mailbox line ----
                u64* m = ml + (size_t)chunk * 8;
                u64 m2;
                do {
                    m2 = __hip_atomic_load(&m[2], __ATOMIC_ACQUIRE,
                                           __HIP_MEMORY_SCOPE_AGENT);
                } while ((u32)(m2 >> 32) != (u32)it);
                u64 m0 = __hip_atomic_load(&m[0], __ATOMIC_RELAXED,
                                           __HIP_MEMORY_SCOPE_AGENT);
                u64 m1 = __hip_atomic_load(&m[1], __ATOMIC_RELAXED,
                                           __HIP_MEMORY_SCOPE_AGENT);
                cx = __uint_as_float((u32)(m0 >> 32));
                cy = __uint_as_float((u32)m0);
                cz = __uint_as_float((u32)(m1 >> 32));
            }
            // ---- fan out to waves 1..7 via LDS (tagged ring-2) ----
            if (lane == 0) {
                __hip_atomic_store(&bcA[par], packf(cx, cy),
                                   __ATOMIC_RELAXED, __HIP_MEMORY_SCOPE_WORKGROUP);
                __hip_atomic_store(&bcB[par],
                                   ((u64)__float_as_uint(cz) << 32) | (u64)(u32)it,
                                   __ATOMIC_RELEASE, __HIP_MEMORY_SCOPE_WORKGROUP);
            }
        } else {
            // ---- other waves: wait for tagged LDS broadcast ----
            u64 bv;
            do {
                bv = __hip_atomic_load(&bcB[par], __ATOMIC_ACQUIRE,
                                       __HIP_MEMORY_SCOPE_WORKGROUP);
            } while ((u32)bv != (u32)it);
            u64 av = __hip_atomic_load(&bcA[par], __ATOMIC_RELAXED,
                                       __HIP_MEMORY_SCOPE_WORKGROUP);
            cz = __uint_as_float((u32)(bv >> 32));
            cx = __uint_as_float((u32)(av >> 32));
            cy = __uint_as_float((u32)av);
        }
    }
}

extern "C" void kernel_launch(void* const* d_in, const int* in_sizes, int n_in,
                              void* d_out, int out_size, void* d_ws, size_t ws_size,
                              hipStream_t stream) {
    const float* xyz = (const float*)d_in[0];
    int* out = (int*)d_out;
    u64* gws = (u64*)d_ws;   // 128 KB: slot lines + mailbox lines

    hipLaunchKernelGGL(fps_init_kernel, dim3(64), dim3(256), 0, stream, gws);
    hipLaunchKernelGGL(fps_kernel, dim3(BATCH * NBLK), dim3(TPB), 0, stream,
                       xyz, out, gws);
}

// Round 8
// 9603.027 us; speedup vs baseline: 11.4998x; 11.4998x over previous
//
#include <hip/hip_runtime.h>
#include <stdint.h>

// Problem: D-FPS. points_xyz (16, 131072, 3) fp32 -> indices (16, 4096) int32.
//
// Round 8: ALL-RELAXED sync protocol. r2-r7 evidence: duration tracks the
// count of agent-scope acquire/release ops (256 spinners -> 20ms; 512 -> 70;
// +1600 rel stores -> 110; 2048 -> 184). Agent acquire emits cache
// invalidation, agent release emits L2 writeback (gfx9xx); spinning on them
// causes chip-wide cache-maintenance storms (r7: 395-509 MB WRITE_SIZE from
// repeated dirty-L2 writebacks). Fix: tag+payload ride in ONE 64-bit word,
// so pure RELAXED atomics suffice (no fences, no maintenance); ring-2
// overwrite ordering holds via the end-to-end value-dependence chain
// (store value <- centroid <- polled words <- other blocks' values).
// Winner coords are NOT in the message: bxyz is immutable, plain loads.
//
//  - Update: points in LDS SoA (float2 xy + float z), conflict-free. (r6)
//  - Topology: 16 blocks/batch, TPB=1024, 1 block/CU, ONE polling wave
//    per block, LDS fanout to the other 15 waves. (r3 — empirically best)

#define BATCH 16
#define NPTS  131072
#define NSAMP 4096
#define NBLK  16                  // blocks per batch
#define TPB   1024                // 16 waves
#define CHUNK (NPTS / NBLK)       // 8192 points per block
#define PPT   (CHUNK / TPB)       // 8 points per thread
#define NWAVE (TPB / 64)

typedef unsigned long long u64;
typedef unsigned int u32;

// Global slot word (8B, one per block per parity):
//   [63:32] dist bits (>=0 -> monotone) | [31:15] idx (17b) | [14:0] iter tag
// Poison 0xAA.. -> tag 0x2AAA; zero-init -> tag 0; live tags are 1..4095.
// LDS red word: same layout. LDS bc word: [63:32] idx | [31:0] iter.

__global__ void fps_init_kernel(u64* __restrict__ ws) {
    int i = blockIdx.x * blockDim.x + threadIdx.x;
    if (i < BATCH * 2 * NBLK) ws[i] = 0ull;
}

__global__ __launch_bounds__(TPB, 4) void fps_kernel(
        const float* __restrict__ xyz, int* __restrict__ out,
        u64* __restrict__ gslot) {
    const int blk   = blockIdx.x;
    const int b     = blk & 15;    // batch: a batch's 16 blocks have constant
    const int chunk = blk >> 4;    // blk%8 -> same XCD (round-robin dispatch)
    const int tid   = threadIdx.x;
    const int w     = tid >> 6;
    const int lane  = tid & 63;

    const float* bxyz = xyz + (size_t)b * NPTS * 3;
    const int base = chunk * CHUNK;

    // ---- LDS: SoA points + sync words (98.6 KB -> 1 block/CU) ----
    __shared__ float2 sxy[CHUNK];          // 64 KB
    __shared__ float  szz[CHUNK];          // 32 KB
    __shared__ u64 red[2][NWAVE];          // 256 B
    __shared__ u64 bc[2];                  // 16 B
    for (int i = tid; i < CHUNK; i += TPB) {
        size_t p = (size_t)(base + i) * 3;
        sxy[i] = make_float2(bxyz[p + 0], bxyz[p + 1]);
        szz[i] = bxyz[p + 2];
    }
    if (tid < 2 * NWAVE) ((u64*)red)[tid] = ~0ull;  // tag 0x7FFF: invalid
    if (tid < 2) bc[tid] = ~0ull;                   // low32 0xFFFFFFFF: invalid
    if (tid == 0 && chunk == 0) out[b * NSAMP] = 0; // iter 0 emits index 0
    __syncthreads();   // staging visibility (only block-wide barrier)

    float pd[PPT];
#pragma unroll
    for (int k = 0; k < PPT; ++k) pd[k] = __builtin_inff();

    float cx = bxyz[0], cy = bxyz[1], cz = bxyz[2];

    u64* gs = gslot + (size_t)b * 2 * NBLK;   // [2][NBLK]

    for (int it = 1; it < NSAMP; ++it) {
        const int par = it & 1;

        // ---- update min-dists + local argmax (LDS + registers) ----
        // Verified arithmetic (round 2, absmax 0): FMA-contracted
        //   d = fma(dz,dz, fma(dy,dy, dx*dx)), subs exact-rounded.
        float bd = -1.0f;
        int   bk = 0;
#pragma unroll
        for (int k = 0; k < PPT; ++k) {
            int i = tid + TPB * k;
            float2 xy = sxy[i];
            float  z  = szz[i];
            float dx = __fsub_rn(xy.x, cx);
            float dy = __fsub_rn(xy.y, cy);
            float dz = __fsub_rn(z,    cz);
            float d  = __builtin_fmaf(dz, dz,
                         __builtin_fmaf(dy, dy, __fmul_rn(dx, dx)));
            float nd = fminf(pd[k], d);
            pd[k] = nd;
            // strict >: earliest k wins (gi ascends with k) = first-occurrence
            if (nd > bd) { bd = nd; bk = k; }
        }
        u32 gi = (u32)(base + tid + TPB * bk);
        u64 key = ((u64)__float_as_uint(bd) << 32) | (u64)(~gi);

        // ---- wave butterfly (max dist, then min index) ----
#pragma unroll
        for (int off = 1; off <= 32; off <<= 1) {
            u64 o = __shfl_xor(key, off, 64);
            key = key > o ? key : o;
        }
        // lane0 publishes the wave best to LDS. Payload+tag in one word ->
        // RELAXED is sufficient; workgroup scope = no cache ops either way.
        if (lane == 0) {
            u32 db  = (u32)(key >> 32);
            u32 idx = ~(u32)key;          // = gi (fits 17 bits)
            __hip_atomic_store(&red[par][w],
                               ((u64)db << 32) | ((u64)idx << 15) | (u64)it,
                               __ATOMIC_RELAXED, __HIP_MEMORY_SCOPE_WORKGROUP);
        }

        if (w == 0) {
            // ---- combine the 16 wave entries from LDS ----
            u64 v; bool ok;
            do {
                v  = (lane < NWAVE)
                       ? __hip_atomic_load(&red[par][lane], __ATOMIC_RELAXED,
                                           __HIP_MEMORY_SCOPE_WORKGROUP)
                       : 0ull;
                ok = (lane < NWAVE) ? ((v & 0x7FFFull) == (u64)it) : true;
            } while (__ballot(ok) != ~0ull);
            u64 k2 = 0ull;
            if (lane < NWAVE) {
                u32 db  = (u32)(v >> 32);
                u32 idx = (u32)((v >> 15) & 0x1FFFFu);
                k2 = ((u64)db << 32) | (u64)(~idx);
            }
#pragma unroll
            for (int off = 1; off <= 8; off <<= 1) {
                u64 o = __shfl_xor(k2, off, 64);
                k2 = k2 > o ? k2 : o;
            }
            // ---- ONE relaxed agent store publishes the block winner ----
            if (lane == 0) {
                u32 db  = (u32)(k2 >> 32);
                u32 idx = ~(u32)k2;
                __hip_atomic_store(&gs[par * NBLK + chunk],
                                   ((u64)db << 32) | ((u64)idx << 15) | (u64)it,
                                   __ATOMIC_RELAXED, __HIP_MEMORY_SCOPE_AGENT);
            }
            // ---- poll the 16 slot words, ALL RELAXED (no cache ops) ----
            do {
                v  = (lane < NBLK)
                       ? __hip_atomic_load(&gs[par * NBLK + lane],
                                           __ATOMIC_RELAXED,
                                           __HIP_MEMORY_SCOPE_AGENT)
                       : 0ull;
                ok = (lane < NBLK) ? ((v & 0x7FFFull) == (u64)it) : true;
            } while (__ballot(ok) != ~0ull);
            u64 k3 = 0ull;
            if (lane < NBLK) {
                u32 db  = (u32)(v >> 32);
                u32 idx = (u32)((v >> 15) & 0x1FFFFu);
                k3 = ((u64)db << 32) | (u64)(~idx);
            }
#pragma unroll
            for (int off = 1; off <= 32; off <<= 1) {  // full: winner on ALL lanes
                u64 o = __shfl_xor(k3, off, 64);
                k3 = k3 > o ? k3 : o;
            }
            u32 widx = ~(u32)k3;    // = winning gi
            if (lane == 0) {
                if (chunk == 0) out[b * NSAMP + it] = (int)widx;
                __hip_atomic_store(&bc[par],
                                   ((u64)widx << 32) | (u64)(u32)it,
                                   __ATOMIC_RELAXED, __HIP_MEMORY_SCOPE_WORKGROUP);
            }
            // coords from immutable bxyz: same-address broadcast load (L1/L2)
            cx = bxyz[3 * (size_t)widx + 0];
            cy = bxyz[3 * (size_t)widx + 1];
            cz = bxyz[3 * (size_t)widx + 2];
        } else {
            // ---- other waves: wait for tagged LDS broadcast ----
            u64 bv;
            do {
                bv = __hip_atomic_load(&bc[par], __ATOMIC_RELAXED,
                                       __HIP_MEMORY_SCOPE_WORKGROUP);
            } while ((u32)bv != (u32)it);
            u32 widx = (u32)(bv >> 32);
            cx = bxyz[3 * (size_t)widx + 0];
            cy = bxyz[3 * (size_t)widx + 1];
            cz = bxyz[3 * (size_t)widx + 2];
        }
    }
}

extern "C" void kernel_launch(void* const* d_in, const int* in_sizes, int n_in,
                              void* d_out, int out_size, void* d_ws, size_t ws_size,
                              hipStream_t stream) {
    const float* xyz = (const float*)d_in[0];
    int* out = (int*)d_out;
    u64* gslot = (u64*)d_ws;   // [BATCH][2][NBLK] u64 = 4 KB

    hipLaunchKernelGGL(fps_init_kernel, dim3(1), dim3(512), 0, stream, gslot);
    hipLaunchKernelGGL(fps_kernel, dim3(BATCH * NBLK), dim3(TPB), 0, stream,
                       xyz, out, gslot);
}